// Round 1
// baseline (33.965 us; speedup 1.0000x reference)
//
#include <hip/hip_runtime.h>

// LengthRegulator: B=32, T=256, D=512, DUR_MAX=12
// out[b, f, :] = xs[b, searchsorted(cumsum(ds[b]), f, 'right').clip(0,T-1), :]
//                if f < total[b] else 0.0
#define BB 32
#define TT 256
#define DD 512
#define DUR_MAX_ 12
#define MAX_FRAMES_ (TT * (DUR_MAX_ - 1))   // 2816
#define FRAMES_PER_BLOCK 32
#define D4 (DD / 4)                          // 128 float4 per frame
#define BLOCK_THREADS 256

__global__ __launch_bounds__(BLOCK_THREADS)
void LengthRegulator_20332375179470_kernel(const float* __restrict__ xs,
                                           const int* __restrict__ ds,
                                           float* __restrict__ out)
{
    __shared__ int s_cs[TT];
    __shared__ int s_tok[FRAMES_PER_BLOCK];

    const int b   = blockIdx.y;
    const int f0  = blockIdx.x * FRAMES_PER_BLOCK;
    const int tid = threadIdx.x;

    // ---- load ds row + inclusive scan (Hillis-Steele, 8 steps) ----
    s_cs[tid] = ds[b * TT + tid];
    __syncthreads();
    #pragma unroll
    for (int off = 1; off < TT; off <<= 1) {
        int v = (tid >= off) ? s_cs[tid - off] : 0;
        __syncthreads();
        s_cs[tid] += v;
        __syncthreads();
    }
    const int total = s_cs[TT - 1];

    // ---- token index per frame: first idx with cs[idx] > f ----
    if (tid < FRAMES_PER_BLOCK) {
        const int f = f0 + tid;
        if (f < total) {
            int lo = 0, hi = TT;
            while (lo < hi) {
                int mid = (lo + hi) >> 1;
                if (s_cs[mid] <= f) lo = mid + 1; else hi = mid;
            }
            if (lo > TT - 1) lo = TT - 1;
            s_tok[tid] = lo;
        } else {
            s_tok[tid] = -1;   // padded frame
        }
    }
    __syncthreads();

    // ---- copy 32 frames x 512 floats as float4, coalesced ----
    const float4* xs4  = (const float4*)(xs + (size_t)b * TT * DD);
    float4*       out4 = (float4*)(out + ((size_t)b * MAX_FRAMES_ + f0) * DD);

    #pragma unroll
    for (int i = 0; i < (FRAMES_PER_BLOCK * D4) / BLOCK_THREADS; ++i) {
        const int l   = i * BLOCK_THREADS + tid;
        const int fl  = l >> 7;        // l / D4
        const int d4  = l & (D4 - 1);  // l % D4
        const int tok = s_tok[fl];
        float4 v = make_float4(0.f, 0.f, 0.f, 0.f);
        if (tok >= 0) v = xs4[tok * D4 + d4];
        out4[l] = v;
    }
}

extern "C" void kernel_launch(void* const* d_in, const int* in_sizes, int n_in,
                              void* d_out, int out_size, void* d_ws, size_t ws_size,
                              hipStream_t stream) {
    const float* xs = (const float*)d_in[0];
    const int*   ds = (const int*)d_in[1];
    float*       out = (float*)d_out;

    dim3 grid(MAX_FRAMES_ / FRAMES_PER_BLOCK, BB);
    LengthRegulator_20332375179470_kernel<<<grid, BLOCK_THREADS, 0, stream>>>(xs, ds, out);
}